// Round 1
// baseline (914.312 us; speedup 1.0000x reference)
//
#include <hip/hip_runtime.h>
#include <hip/hip_bf16.h>
#include <math.h>

#define T_LEN   320000
#define NB      16
#define NROWS   32          // 16 batch * 2 ch
#define NFRAMES 625
#define NCOMP   67
#define NCH     150
#define HOPSZ   512

// per-window constants: N, first bin k0, comp base, coeff base (float2 units)
__constant__ int cW_N[6]  = {2048,1024,512,256,128,64};
__constant__ int cW_K0[6] = {2,3,8,10,11,9};
__constant__ int cW_CB[7] = {0,4,17,29,40,46,67};
__constant__ int cW_CO[7] = {0,8192,21504,27648,30464,31232,32576};

// ---------------- init: DFT coeff tables, roex matrix, gauss weights ----------------
__global__ void init_tables(float2* __restrict__ coeff, float* __restrict__ Wmat,
                            float* __restrict__ gauss) {
  int gid = blockIdx.x * 256 + threadIdx.x;
  if (gid < 32576) {
    int w = 0;
    while (gid >= cW_CO[w + 1]) ++w;
    int local = gid - cW_CO[w];
    int N = cW_N[w];
    int jloc = local / N;
    int n = local - jloc * N;
    int k = cW_K0[w] + jloc;
    // Hann window; win_sum = 0.5*(N-1) analytically
    float win = 0.5f - 0.5f * cospif(2.0f * (float)n / (float)(N - 1));
    int r = (int)(((long long)k * (long long)n) % (long long)N);
    float ang = 2.0f * (float)r / (float)N;            // in pi units
    float scale = sqrtf(2.0f) / (0.5f * (float)(N - 1));
    float wc = win * scale;                             // folds 0.5*(2/winsum)^2 into coeffs
    coeff[gid] = make_float2(wc * cospif(ang), wc * sinpif(ang));
  } else if (gid < 32576 + NCOMP * NCH) {
    int t = gid - 32576;
    int j = t / NCH, c = t - j * NCH;
    float erb = 1.75f + 0.25f * (float)c;
    float fc = (exp10f(erb * (1.0f / 21.366f)) - 1.0f) * (1.0f / 0.004368f);
    float erbw = 24.673f * (0.004368f * fc + 1.0f);
    float p = 4.0f * fc / erbw;
    int w = 0;
    while (j >= cW_CB[w + 1]) ++w;
    float freq = (float)(cW_K0[w] + (j - cW_CB[w])) * (32000.0f / (float)cW_N[w]);
    float g = fabsf(freq / fc - 1.0f);
    float pg = p * g;
    Wmat[j * NCH + c] = (1.0f + pg) * expf(-pg);
  } else if (gid == 32576 + NCOMP * NCH) {
    float tmp[17]; float s = 0.0f;
    for (int k = 0; k < 17; ++k) {
      float g = ((float)k - 8.0f) * 0.25f;
      tmp[k] = expf(-g * g / (2.0f * 0.08f * 0.08f));
      s += tmp[k];
    }
    for (int k = 0; k < 17; ++k) gauss[k] = tmp[k] / s;
  }
}

// ---------------- ear FIR: y[n] = sum_{m=0}^{1024} h[m] * x[n+512-m] ----------------
#define CT 4096   // outputs per block (256 threads * 16)
__global__ __launch_bounds__(256) void ear_conv(const float* __restrict__ x,
                                                const float* __restrict__ h,
                                                float* __restrict__ y) {
  __shared__ __align__(16) float xs[CT + 1024];
  __shared__ float hs[1025];
  const int row = blockIdx.y;
  const size_t rowoff = (size_t)row * T_LEN;
  const int t0 = blockIdx.x * CT;
  const int tid = threadIdx.x;
  for (int i = tid; i < CT + 1024; i += 256) {
    int g = t0 - 512 + i;
    xs[i] = ((unsigned)g < (unsigned)T_LEN) ? x[rowoff + g] : 0.0f;
  }
  for (int i = tid; i < 1025; i += 256) hs[i] = h[i];
  __syncthreads();
  const int base = tid * 16;
  float acc[16], w[16];
#pragma unroll
  for (int r = 0; r < 16; ++r) { acc[r] = 0.0f; w[r] = xs[base + r]; }
  const float4* xs4 = (const float4*)xs;
  // term q (=1024-m): acc[r] += h[1024-q] * xs[base+q+r], q = 0..1024
  for (int q0 = 0; q0 < 1024; q0 += 16) {
    float4 v0 = xs4[(base + q0 + 16) >> 2];
    float4 v1 = xs4[(base + q0 + 20) >> 2];
    float4 v2 = xs4[(base + q0 + 24) >> 2];
    float4 v3 = xs4[(base + q0 + 28) >> 2];
    float nw[16] = {v0.x, v0.y, v0.z, v0.w, v1.x, v1.y, v1.z, v1.w,
                    v2.x, v2.y, v2.z, v2.w, v3.x, v3.y, v3.z, v3.w};
#pragma unroll
    for (int u = 0; u < 16; ++u) {
      float hv = hs[1024 - q0 - u];
#pragma unroll
      for (int r = 0; r < 16; ++r) acc[r] = fmaf(hv, w[(u + r) & 15], acc[r]);
      w[u] = nw[u];
    }
  }
  {
    float hv = hs[0];
#pragma unroll
    for (int r = 0; r < 16; ++r) acc[r] = fmaf(hv, w[r], acc[r]);
  }
#pragma unroll
  for (int r = 0; r < 16; ++r) {
    int n = t0 + base + r;
    if (n < T_LEN) y[rowoff + n] = acc[r];
  }
}

// ---------------- sparse multi-window DFT -> I[row][f][67] ----------------
#define FPB 8
__global__ __launch_bounds__(256) void sparse_dft(const float* __restrict__ y,
                                                  const float2* __restrict__ coeff,
                                                  float* __restrict__ Ibuf) {
  __shared__ float ylds[5632];   // covers 8 frames: 2048-window of first .. last
  const int row = blockIdx.y;
  const int f0 = blockIdx.x * FPB;
  const size_t rowoff = (size_t)row * T_LEN;
  const int lo = f0 * HOPSZ - 1024;
  const int tid = threadIdx.x;
  for (int i = tid; i < 5632; i += 256) {
    int g = lo + i;
    ylds[i] = ((unsigned)g < (unsigned)T_LEN) ? y[rowoff + g] : 0.0f;
  }
  __syncthreads();
  const int wv = tid >> 6, lane = tid & 63;
  for (int p = wv; p < NCOMP * FPB; p += 4) {   // p = j*8 + fr
    int j = p >> 3, fr = p & 7;
    int f = f0 + fr;
    if (f >= NFRAMES) continue;
    int w = 0;
    while (j >= cW_CB[w + 1]) ++w;
    int N = cW_N[w];
    const float2* cf = coeff + cW_CO[w] + (size_t)(j - cW_CB[w]) * N;
    int st = 1024 + fr * HOPSZ - (N >> 1);
    float re = 0.0f, im = 0.0f;
    for (int i = lane; i < N; i += 64) {
      float2 cs = cf[i];
      float yv = ylds[st + i];
      re = fmaf(yv, cs.x, re);
      im = fmaf(yv, cs.y, im);
    }
#pragma unroll
    for (int off = 32; off > 0; off >>= 1) {
      re += __shfl_xor(re, off);
      im += __shfl_xor(im, off);
    }
    if (lane == 0) Ibuf[((size_t)row * NFRAMES + f) * NCOMP + j] = re * re + im * im;
  }
}

// ---------------- E = I@W -> dB -> LUT interp -> n_inst[row][f][150] ----------------
__global__ __launch_bounds__(192) void espec(const float* __restrict__ Ibuf,
                                             const float* __restrict__ Wmat,
                                             const float* __restrict__ lut,
                                             float* __restrict__ ninst) {
  const int blk = blockIdx.x;           // row*625 + f
  const int c = threadIdx.x;
  const float* Irow = Ibuf + (size_t)blk * NCOMP;
  if (c < NCH) {
    float e = 0.0f;
    for (int j = 0; j < NCOMP; ++j) e = fmaf(Irow[j], Wmat[j * NCH + c], e);
    float edb = 10.0f * log10f(e * 2.5e9f + 1e-12f);   // 1/I0 = 2.5e9
    float xv = fminf(fmaxf(edb, 0.0f), 110.0f);
    float u = xv * (87.0f / 110.0f);
    int i0 = (int)u; if (i0 > 86) i0 = 86;
    float fr = u - (float)i0;
    float nv = fmaf(lut[i0 + 1] - lut[i0], fr, lut[i0]);
    ninst[(size_t)blk * NCH + c] = nv;
  }
}

// ---------------- short-term AGC over frames ----------------
__global__ void agc1(const float* __restrict__ ninst, float* __restrict__ stl) {
  int idx = blockIdx.x * 256 + threadIdx.x;
  if (idx >= NROWS * NCH) return;
  int row = idx / NCH, c = idx - row * NCH;
  const float* src = ninst + (size_t)row * NFRAMES * NCH + c;
  float* dst = stl + (size_t)row * NFRAMES * NCH + c;
  float s = 0.0f;
  for (int f = 0; f < NFRAMES; ++f) {
    float xv = src[(size_t)f * NCH];
    float a = (xv > s) ? 0.045f : 0.033f;
    s = a * xv + (1.0f - a) * s;
    dst[(size_t)f * NCH] = s;
  }
}

// ---------------- ERB smoothing + binaural inhibition + channel sum ----------------
__global__ __launch_bounds__(192) void combine(const float* __restrict__ stl,
                                               const float* __restrict__ gauss,
                                               float* __restrict__ outL,
                                               float* __restrict__ outR) {
  __shared__ float sl[NCH + 16], sr[NCH + 16], gsh[17];
  __shared__ float redL[3], redR[3];
  const int bf = blockIdx.x;
  const int b = bf / NFRAMES, f = bf - b * NFRAMES;
  const int tid = threadIdx.x;
  if (tid < NCH + 16) { sl[tid] = 0.0f; sr[tid] = 0.0f; }
  if (tid < 17) gsh[tid] = gauss[tid];
  __syncthreads();
  if (tid < NCH) {
    sl[8 + tid] = stl[((size_t)(b * 2 + 0) * NFRAMES + f) * NCH + tid];
    sr[8 + tid] = stl[((size_t)(b * 2 + 1) * NFRAMES + f) * NCH + tid];
  }
  __syncthreads();
  float vl = 0.0f, vr = 0.0f;
  if (tid < NCH) {
    float smL = 0.0f, smR = 0.0f;
#pragma unroll
    for (int t = 0; t < 17; ++t) {
      smL = fmaf(gsh[t], sl[tid + t], smL);
      smR = fmaf(gsh[t], sr[tid + t], smR);
    }
    vl = smL / coshf(1.5978f * smR);
    vr = smR / coshf(1.5978f * smL);
  }
#pragma unroll
  for (int off = 32; off > 0; off >>= 1) {
    vl += __shfl_xor(vl, off);
    vr += __shfl_xor(vr, off);
  }
  int wv = tid >> 6, lane = tid & 63;
  if (lane == 0) { redL[wv] = vl; redR[wv] = vr; }
  __syncthreads();
  if (tid == 0) {
    outL[bf] = (redL[0] + redL[1] + redL[2]) * 0.25f;
    outR[bf] = (redR[0] + redR[1] + redR[2]) * 0.25f;
  }
}

// ---------------- long-term AGC + outputs ----------------
__global__ void final_k(const float* __restrict__ sLst, const float* __restrict__ sRst,
                        float* __restrict__ out) {
  int b = threadIdx.x;
  if (b >= NB) return;
  float ll = 0.0f, lr = 0.0f, mx = -3.4e38f;
  float* sOut = out;
  float* lOut = out + NB * NFRAMES;
  float* mOut = out + 2 * NB * NFRAMES;
  for (int f = 0; f < NFRAMES; ++f) {
    float a = sLst[b * NFRAMES + f];
    float c = sRst[b * NFRAMES + f];
    sOut[b * NFRAMES + f] = a + c;
    float aa = (a > ll) ? 0.01f : 0.00133f;
    ll = aa * a + (1.0f - aa) * ll;
    float ab = (c > lr) ? 0.01f : 0.00133f;
    lr = ab * c + (1.0f - ab) * lr;
    float lv = ll + lr;
    lOut[b * NFRAMES + f] = lv;
    mx = fmaxf(mx, lv);
  }
  mOut[b] = mx;
}

extern "C" void kernel_launch(void* const* d_in, const int* in_sizes, int n_in,
                              void* d_out, int out_size, void* d_ws, size_t ws_size,
                              hipStream_t stream) {
  const float* audio = (const float*)d_in[0];
  const float* ear   = (const float*)d_in[1];
  const float* lut   = (const float*)d_in[2];
  char* ws = (char*)d_ws;

  float*  y     = (float*)(ws);                          // 40,960,000 B
  float2* coeff = (float2*)(ws + 40960000);              //    260,608 B
  float*  Wmat  = (float*)(ws + 41220608);               //     40,200 B
  float*  gauss = (float*)(ws + 41260864);               //         68 B (8-aligned)
  float*  Ibuf  = (float*)(ws + 41260992);               //  5,360,000 B
  float*  stlL  = (float*)(ws + 46621056);               //     40,000 B
  float*  stlR  = (float*)(ws + 46661056);               //     40,000 B
  // aliases into dead y-region (y unused after sparse_dft):
  float*  ninst = (float*)(ws);                          // 12,000,000 B
  float*  stl   = (float*)(ws + 16000000);               // 12,000,000 B

  hipLaunchKernelGGL(init_tables, dim3(167), dim3(256), 0, stream, coeff, Wmat, gauss);
  hipLaunchKernelGGL(ear_conv, dim3(79, 32), dim3(256), 0, stream, audio, ear, y);
  hipLaunchKernelGGL(sparse_dft, dim3(79, 32), dim3(256), 0, stream, y, coeff, Ibuf);
  hipLaunchKernelGGL(espec, dim3(NROWS * NFRAMES), dim3(192), 0, stream, Ibuf, Wmat, lut, ninst);
  hipLaunchKernelGGL(agc1, dim3(19), dim3(256), 0, stream, ninst, stl);
  hipLaunchKernelGGL(combine, dim3(NB * NFRAMES), dim3(192), 0, stream, stl, gauss, stlL, stlR);
  hipLaunchKernelGGL(final_k, dim3(1), dim3(64), 0, stream, stlL, stlR, (float*)d_out);
}

// Round 2
// 529.656 us; speedup vs baseline: 1.7262x; 1.7262x over previous
//
#include <hip/hip_runtime.h>
#include <hip/hip_bf16.h>
#include <math.h>

#define T_LEN   320000
#define NB      16
#define NROWS   32          // 16 batch * 2 ch
#define NFRAMES 625
#define NCOMP   67
#define NCH     150
#define HOPSZ   512

// per-window constants: N, first bin k0, comp base, coeff base (float2 units)
__constant__ int cW_N[6]  = {2048,1024,512,256,128,64};
__constant__ int cW_K0[6] = {2,3,8,10,11,9};
__constant__ int cW_CB[7] = {0,4,17,29,40,46,67};
__constant__ int cW_CO[7] = {0,8192,21504,27648,30464,31232,32576};

// ---------------- init: DFT coeff tables, roex matrix, gauss weights ----------------
__global__ void init_tables(float2* __restrict__ coeff, float* __restrict__ Wmat,
                            float* __restrict__ gauss) {
  int gid = blockIdx.x * 256 + threadIdx.x;
  if (gid < 32576) {
    int w = 0;
    while (gid >= cW_CO[w + 1]) ++w;
    int local = gid - cW_CO[w];
    int N = cW_N[w];
    int jloc = local / N;
    int n = local - jloc * N;
    int k = cW_K0[w] + jloc;
    // Hann window; win_sum = 0.5*(N-1) analytically
    float win = 0.5f - 0.5f * cospif(2.0f * (float)n / (float)(N - 1));
    int r = (int)(((long long)k * (long long)n) % (long long)N);
    float ang = 2.0f * (float)r / (float)N;            // in pi units
    float scale = sqrtf(2.0f) / (0.5f * (float)(N - 1));
    float wc = win * scale;                             // folds 0.5*(2/winsum)^2 into coeffs
    coeff[gid] = make_float2(wc * cospif(ang), wc * sinpif(ang));
  } else if (gid < 32576 + NCOMP * NCH) {
    int t = gid - 32576;
    int j = t / NCH, c = t - j * NCH;
    float erb = 1.75f + 0.25f * (float)c;
    float fc = (exp10f(erb * (1.0f / 21.366f)) - 1.0f) * (1.0f / 0.004368f);
    float erbw = 24.673f * (0.004368f * fc + 1.0f);
    float p = 4.0f * fc / erbw;
    int w = 0;
    while (j >= cW_CB[w + 1]) ++w;
    float freq = (float)(cW_K0[w] + (j - cW_CB[w])) * (32000.0f / (float)cW_N[w]);
    float g = fabsf(freq / fc - 1.0f);
    float pg = p * g;
    Wmat[j * NCH + c] = (1.0f + pg) * expf(-pg);
  } else if (gid == 32576 + NCOMP * NCH) {
    float tmp[17]; float s = 0.0f;
    for (int k = 0; k < 17; ++k) {
      float g = ((float)k - 8.0f) * 0.25f;
      tmp[k] = expf(-g * g / (2.0f * 0.08f * 0.08f));
      s += tmp[k];
    }
    for (int k = 0; k < 17; ++k) gauss[k] = tmp[k] / s;
  }
}

// ---------------- ear FIR: y[n] = sum_{m=0}^{1024} h[m] * x[n+512-m] ----------------
#define CT 4096   // outputs per block (256 threads * 16)
__global__ __launch_bounds__(256) void ear_conv(const float* __restrict__ x,
                                                const float* __restrict__ h,
                                                float* __restrict__ y) {
  __shared__ __align__(16) float xs[CT + 1024];
  __shared__ float hs[1025];
  const int row = blockIdx.y;
  const size_t rowoff = (size_t)row * T_LEN;
  const int t0 = blockIdx.x * CT;
  const int tid = threadIdx.x;
  for (int i = tid; i < CT + 1024; i += 256) {
    int g = t0 - 512 + i;
    xs[i] = ((unsigned)g < (unsigned)T_LEN) ? x[rowoff + g] : 0.0f;
  }
  for (int i = tid; i < 1025; i += 256) hs[i] = h[i];
  __syncthreads();
  const int base = tid * 16;
  float acc[16], w[16];
#pragma unroll
  for (int r = 0; r < 16; ++r) { acc[r] = 0.0f; w[r] = xs[base + r]; }
  const float4* xs4 = (const float4*)xs;
  // term q (=1024-m): acc[r] += h[1024-q] * xs[base+q+r], q = 0..1024
  for (int q0 = 0; q0 < 1024; q0 += 16) {
    float4 v0 = xs4[(base + q0 + 16) >> 2];
    float4 v1 = xs4[(base + q0 + 20) >> 2];
    float4 v2 = xs4[(base + q0 + 24) >> 2];
    float4 v3 = xs4[(base + q0 + 28) >> 2];
    float nw[16] = {v0.x, v0.y, v0.z, v0.w, v1.x, v1.y, v1.z, v1.w,
                    v2.x, v2.y, v2.z, v2.w, v3.x, v3.y, v3.z, v3.w};
#pragma unroll
    for (int u = 0; u < 16; ++u) {
      float hv = hs[1024 - q0 - u];
#pragma unroll
      for (int r = 0; r < 16; ++r) acc[r] = fmaf(hv, w[(u + r) & 15], acc[r]);
      w[u] = nw[u];
    }
  }
  {
    float hv = hs[0];
#pragma unroll
    for (int r = 0; r < 16; ++r) acc[r] = fmaf(hv, w[r], acc[r]);
  }
#pragma unroll
  for (int r = 0; r < 16; ++r) {
    int n = t0 + base + r;
    if (n < T_LEN) y[rowoff + n] = acc[r];
  }
}

// ---------------- sparse multi-window DFT -> I[row][f][67] ----------------
// One block: 8 frames x all 67 comps for one row. Each wave register-blocks
// the 8 frames so every coeff float4 is loaded once and feeds 32 FMAs.
#define FPB 8
__device__ __forceinline__ float fold_xor(float a, float b, int m, int lane) {
  float x = (lane & m) ? b : a;
  float y = (lane & m) ? a : b;
  return x + __shfl_xor(y, m);
}

__global__ __launch_bounds__(256) void sparse_dft(const float* __restrict__ y,
                                                  const float2* __restrict__ coeff,
                                                  float* __restrict__ Ibuf) {
  __shared__ __align__(16) float ylds[5632];   // covers 8 frames: 2048-window span
  const int row = blockIdx.y;
  const int f0 = blockIdx.x * FPB;
  const size_t rowoff = (size_t)row * T_LEN;
  const int lo = f0 * HOPSZ - 1024;
  const int tid = threadIdx.x;
  for (int i = tid; i < 5632; i += 256) {
    int g = lo + i;
    ylds[i] = ((unsigned)g < (unsigned)T_LEN) ? y[rowoff + g] : 0.0f;
  }
  __syncthreads();
  const int wv = tid >> 6, lane = tid & 63;
  for (int j = wv; j < NCOMP; j += 4) {
    int w = 0;
    while (j >= cW_CB[w + 1]) ++w;
    const int N = cW_N[w];
    const float4* cf4 = (const float4*)(coeff + cW_CO[w] + (size_t)(j - cW_CB[w]) * N);
    const int stbase = 1024 - (N >> 1);
    float re[FPB], im[FPB];
#pragma unroll
    for (int fr = 0; fr < FPB; ++fr) { re[fr] = 0.0f; im[fr] = 0.0f; }
    for (int i = 2 * lane; i < N; i += 128) {
      float4 c01 = cf4[i >> 1];          // taps i, i+1: (cos_i, sin_i, cos_i1, sin_i1)
#pragma unroll
      for (int fr = 0; fr < FPB; ++fr) {
        float2 yv = *(const float2*)&ylds[stbase + fr * HOPSZ + i];
        re[fr] = fmaf(yv.x, c01.x, re[fr]);
        im[fr] = fmaf(yv.x, c01.y, im[fr]);
        re[fr] = fmaf(yv.y, c01.z, re[fr]);
        im[fr] = fmaf(yv.y, c01.w, im[fr]);
      }
    }
    // fold-reduce 16 accumulators across 64 lanes:
    //   final lane bits: b0..b2 = frame, b3 = re/im
    float rr[4], ii[4];
#pragma unroll
    for (int k = 0; k < 4; ++k) {
      rr[k] = fold_xor(re[2 * k], re[2 * k + 1], 1, lane);
      ii[k] = fold_xor(im[2 * k], im[2 * k + 1], 1, lane);
    }
    float r2[2], i2[2];
#pragma unroll
    for (int k = 0; k < 2; ++k) {
      r2[k] = fold_xor(rr[2 * k], rr[2 * k + 1], 2, lane);
      i2[k] = fold_xor(ii[2 * k], ii[2 * k + 1], 2, lane);
    }
    float r3 = fold_xor(r2[0], r2[1], 4, lane);
    float i3 = fold_xor(i2[0], i2[1], 4, lane);
    float v = fold_xor(r3, i3, 8, lane);
    v += __shfl_xor(v, 16);
    v += __shfl_xor(v, 32);
    float sq = v * v;
    sq += __shfl_xor(sq, 8);             // re^2 + im^2 lands in lanes with bit3==0
    if (lane < 8) {
      int f = f0 + lane;
      if (f < NFRAMES) Ibuf[((size_t)row * NFRAMES + f) * NCOMP + j] = sq;
    }
  }
}

// ---------------- E = I@W -> dB -> LUT interp -> n_inst[row][f][150] ----------------
__global__ __launch_bounds__(192) void espec(const float* __restrict__ Ibuf,
                                             const float* __restrict__ Wmat,
                                             const float* __restrict__ lut,
                                             float* __restrict__ ninst) {
  const int blk = blockIdx.x;           // row*625 + f
  const int c = threadIdx.x;
  const float* Irow = Ibuf + (size_t)blk * NCOMP;
  if (c < NCH) {
    float e = 0.0f;
    for (int j = 0; j < NCOMP; ++j) e = fmaf(Irow[j], Wmat[j * NCH + c], e);
    float edb = 10.0f * log10f(e * 2.5e9f + 1e-12f);   // 1/I0 = 2.5e9
    float xv = fminf(fmaxf(edb, 0.0f), 110.0f);
    float u = xv * (87.0f / 110.0f);
    int i0 = (int)u; if (i0 > 86) i0 = 86;
    float fr = u - (float)i0;
    float nv = fmaf(lut[i0 + 1] - lut[i0], fr, lut[i0]);
    ninst[(size_t)blk * NCH + c] = nv;
  }
}

// ---------------- short-term AGC over frames ----------------
__global__ void agc1(const float* __restrict__ ninst, float* __restrict__ stl) {
  int idx = blockIdx.x * 256 + threadIdx.x;
  if (idx >= NROWS * NCH) return;
  int row = idx / NCH, c = idx - row * NCH;
  const float* src = ninst + (size_t)row * NFRAMES * NCH + c;
  float* dst = stl + (size_t)row * NFRAMES * NCH + c;
  float s = 0.0f;
  for (int f = 0; f < NFRAMES; ++f) {
    float xv = src[(size_t)f * NCH];
    float a = (xv > s) ? 0.045f : 0.033f;
    s = a * xv + (1.0f - a) * s;
    dst[(size_t)f * NCH] = s;
  }
}

// ---------------- ERB smoothing + binaural inhibition + channel sum ----------------
__global__ __launch_bounds__(192) void combine(const float* __restrict__ stl,
                                               const float* __restrict__ gauss,
                                               float* __restrict__ outL,
                                               float* __restrict__ outR) {
  __shared__ float sl[NCH + 16], sr[NCH + 16], gsh[17];
  __shared__ float redL[3], redR[3];
  const int bf = blockIdx.x;
  const int b = bf / NFRAMES, f = bf - b * NFRAMES;
  const int tid = threadIdx.x;
  if (tid < NCH + 16) { sl[tid] = 0.0f; sr[tid] = 0.0f; }
  if (tid < 17) gsh[tid] = gauss[tid];
  __syncthreads();
  if (tid < NCH) {
    sl[8 + tid] = stl[((size_t)(b * 2 + 0) * NFRAMES + f) * NCH + tid];
    sr[8 + tid] = stl[((size_t)(b * 2 + 1) * NFRAMES + f) * NCH + tid];
  }
  __syncthreads();
  float vl = 0.0f, vr = 0.0f;
  if (tid < NCH) {
    float smL = 0.0f, smR = 0.0f;
#pragma unroll
    for (int t = 0; t < 17; ++t) {
      smL = fmaf(gsh[t], sl[tid + t], smL);
      smR = fmaf(gsh[t], sr[tid + t], smR);
    }
    vl = smL / coshf(1.5978f * smR);
    vr = smR / coshf(1.5978f * smL);
  }
#pragma unroll
  for (int off = 32; off > 0; off >>= 1) {
    vl += __shfl_xor(vl, off);
    vr += __shfl_xor(vr, off);
  }
  int wv = tid >> 6, lane = tid & 63;
  if (lane == 0) { redL[wv] = vl; redR[wv] = vr; }
  __syncthreads();
  if (tid == 0) {
    outL[bf] = (redL[0] + redL[1] + redL[2]) * 0.25f;
    outR[bf] = (redR[0] + redR[1] + redR[2]) * 0.25f;
  }
}

// ---------------- long-term AGC + outputs ----------------
__global__ void final_k(const float* __restrict__ sLst, const float* __restrict__ sRst,
                        float* __restrict__ out) {
  int b = threadIdx.x;
  if (b >= NB) return;
  float ll = 0.0f, lr = 0.0f, mx = -3.4e38f;
  float* sOut = out;
  float* lOut = out + NB * NFRAMES;
  float* mOut = out + 2 * NB * NFRAMES;
  for (int f = 0; f < NFRAMES; ++f) {
    float a = sLst[b * NFRAMES + f];
    float c = sRst[b * NFRAMES + f];
    sOut[b * NFRAMES + f] = a + c;
    float aa = (a > ll) ? 0.01f : 0.00133f;
    ll = aa * a + (1.0f - aa) * ll;
    float ab = (c > lr) ? 0.01f : 0.00133f;
    lr = ab * c + (1.0f - ab) * lr;
    float lv = ll + lr;
    lOut[b * NFRAMES + f] = lv;
    mx = fmaxf(mx, lv);
  }
  mOut[b] = mx;
}

extern "C" void kernel_launch(void* const* d_in, const int* in_sizes, int n_in,
                              void* d_out, int out_size, void* d_ws, size_t ws_size,
                              hipStream_t stream) {
  const float* audio = (const float*)d_in[0];
  const float* ear   = (const float*)d_in[1];
  const float* lut   = (const float*)d_in[2];
  char* ws = (char*)d_ws;

  float*  y     = (float*)(ws);                          // 40,960,000 B
  float2* coeff = (float2*)(ws + 40960000);              //    260,608 B
  float*  Wmat  = (float*)(ws + 41220608);               //     40,200 B
  float*  gauss = (float*)(ws + 41260864);               //         68 B (8-aligned)
  float*  Ibuf  = (float*)(ws + 41260992);               //  5,360,000 B
  float*  stlL  = (float*)(ws + 46621056);               //     40,000 B
  float*  stlR  = (float*)(ws + 46661056);               //     40,000 B
  // aliases into dead y-region (y unused after sparse_dft):
  float*  ninst = (float*)(ws);                          // 12,000,000 B
  float*  stl   = (float*)(ws + 16000000);               // 12,000,000 B

  hipLaunchKernelGGL(init_tables, dim3(167), dim3(256), 0, stream, coeff, Wmat, gauss);
  hipLaunchKernelGGL(ear_conv, dim3(79, 32), dim3(256), 0, stream, audio, ear, y);
  hipLaunchKernelGGL(sparse_dft, dim3(79, 32), dim3(256), 0, stream, y, coeff, Ibuf);
  hipLaunchKernelGGL(espec, dim3(NROWS * NFRAMES), dim3(192), 0, stream, Ibuf, Wmat, lut, ninst);
  hipLaunchKernelGGL(agc1, dim3(19), dim3(256), 0, stream, ninst, stl);
  hipLaunchKernelGGL(combine, dim3(NB * NFRAMES), dim3(192), 0, stream, stl, gauss, stlL, stlR);
  hipLaunchKernelGGL(final_k, dim3(1), dim3(64), 0, stream, stlL, stlR, (float*)d_out);
}

// Round 3
// 511.173 us; speedup vs baseline: 1.7887x; 1.0362x over previous
//
#include <hip/hip_runtime.h>
#include <hip/hip_bf16.h>
#include <math.h>

#define T_LEN   320000
#define NB      16
#define NROWS   32          // 16 batch * 2 ch
#define NFRAMES 625
#define NCOMP   67
#define NCH     150
#define HOPSZ   512

// per-window constants: N, first bin k0, comp base, coeff base (float2 units)
__constant__ int cW_N[6]  = {2048,1024,512,256,128,64};
__constant__ int cW_K0[6] = {2,3,8,10,11,9};
__constant__ int cW_CB[7] = {0,4,17,29,40,46,67};
__constant__ int cW_CO[7] = {0,8192,21504,27648,30464,31232,32576};

// fused-coefficient table geometry (per window): padded/real lengths, base offsets (float2), x-tile start offset
__constant__ int dNEp[6]  = {3072,2048,1536,1280,1152,1152};
__constant__ int dNEr[6]  = {3072,2048,1536,1280,1152,1088};
__constant__ int dFB[6]   = {0,12288,38912,57344,71424,78336};   // total 102528 float2
__constant__ int dStb[6]  = {0,512,768,896,960,992};             // 1536 - (N+1024)/2
// balanced pass list: wave wv takes passes [dPS[wv], dPS[wv+1])
__constant__ int dPS[5]   = {0,8,16,25,35};
__constant__ int dPW[35]  = {0,1,2,2,3,4,5,1, 0,1,2,2,3,4,5,5, 1,1,2,3,3,4,5,5,5, 1,1,2,3,5,5,5,5,3,5};
__constant__ int dPJ[35]  = {0,4,17,19,29,40,46,16, 2,6,21,23,31,42,48,50, 8,10,25,33,35,44,52,54,56, 12,14,27,37,58,60,62,64,39,66};
__constant__ int dPC[35]  = {2,2,2,2,2,2,2,1, 2,2,2,2,2,2,2,2, 2,2,2,2,2,2,2,2,2, 2,2,2,2,2,2,2,2,1,1};
// init_fused chunk mapping
__constant__ int dCPB[6]  = {12,8,6,5,5,5};                      // chunks per bin (256-wide)
__constant__ int dCKB[7]  = {0,48,152,224,279,309,414};

// ---------------- init: original DFT coeff tables, roex matrix, gauss weights ----------------
__global__ void init_tables(float2* __restrict__ coeff, float* __restrict__ Wmat,
                            float* __restrict__ gauss) {
  int gid = blockIdx.x * 256 + threadIdx.x;
  if (gid < 32576) {
    int w = 0;
    while (gid >= cW_CO[w + 1]) ++w;
    int local = gid - cW_CO[w];
    int N = cW_N[w];
    int jloc = local / N;
    int n = local - jloc * N;
    int k = cW_K0[w] + jloc;
    float win = 0.5f - 0.5f * cospif(2.0f * (float)n / (float)(N - 1));
    int r = (int)(((long long)k * (long long)n) % (long long)N);
    float ang = 2.0f * (float)r / (float)N;
    float scale = sqrtf(2.0f) / (0.5f * (float)(N - 1));
    float wc = win * scale;
    coeff[gid] = make_float2(wc * cospif(ang), wc * sinpif(ang));
  } else if (gid < 32576 + NCOMP * NCH) {
    int t = gid - 32576;
    int j = t / NCH, c = t - j * NCH;
    float erb = 1.75f + 0.25f * (float)c;
    float fc = (exp10f(erb * (1.0f / 21.366f)) - 1.0f) * (1.0f / 0.004368f);
    float erbw = 24.673f * (0.004368f * fc + 1.0f);
    float p = 4.0f * fc / erbw;
    int w = 0;
    while (j >= cW_CB[w + 1]) ++w;
    float freq = (float)(cW_K0[w] + (j - cW_CB[w])) * (32000.0f / (float)cW_N[w]);
    float g = fabsf(freq / fc - 1.0f);
    float pg = p * g;
    Wmat[j * NCH + c] = (1.0f + pg) * expf(-pg);
  } else if (gid == 32576 + NCOMP * NCH) {
    float tmp[17]; float s = 0.0f;
    for (int k = 0; k < 17; ++k) {
      float g = ((float)k - 8.0f) * 0.25f;
      tmp[k] = expf(-g * g / (2.0f * 0.08f * 0.08f));
      s += tmp[k];
    }
    for (int k = 0; k < 17; ++k) gauss[k] = tmp[k] / s;
  }
}

// ---------------- init_fused: C_j[v] = sum_n c_n * h[n + 1024 - v] ----------------
__global__ __launch_bounds__(256) void init_fused(const float* __restrict__ h,
                                                  float2* __restrict__ fusedC) {
  __shared__ float cre_l[1280], cim_l[1280], hs[1025];
  const int bid = blockIdx.x, tid = threadIdx.x;
  int w = 0;
  while (bid >= dCKB[w + 1]) ++w;
  const int local = bid - dCKB[w];
  const int jloc = local / dCPB[w];
  const int chunk = local - jloc * dCPB[w];
  const int j = cW_CB[w] + jloc;
  const int N = cW_N[w];
  const int k = cW_K0[w] + jloc;
  const int NEp = dNEp[w], NEr = dNEr[w];
  const int v0 = chunk * 256;
  const int nlo_blk = max(0, v0 - 1024);
  const int nhi_blk = min(N - 1, v0 + 255);
  const int cnt_n = nhi_blk - nlo_blk + 1;
  const float scale = sqrtf(2.0f) / (0.5f * (float)(N - 1));
  for (int i = tid; i < 1025; i += 256) hs[i] = h[i];
  for (int i = tid; i < cnt_n; i += 256) {
    int n = nlo_blk + i;
    float win = 0.5f - 0.5f * cospif(2.0f * (float)n / (float)(N - 1));
    int r = (int)(((long long)k * (long long)n) % (long long)N);
    float ang = 2.0f * (float)r / (float)N;
    float wc = win * scale;
    cre_l[i] = wc * cospif(ang);
    cim_l[i] = wc * sinpif(ang);
  }
  __syncthreads();
  const int v = v0 + tid;
  if (v >= NEp) return;
  float2 out = make_float2(0.0f, 0.0f);
  if (v < NEr) {
    float re = 0.0f, im = 0.0f;
    for (int n = nlo_blk; n <= nhi_blk; ++n) {
      int hidx = n + 1024 - v;
      if ((unsigned)hidx <= 1024u) {
        float hv = hs[hidx];
        re = fmaf(cre_l[n - nlo_blk], hv, re);
        im = fmaf(cim_l[n - nlo_blk], hv, im);
      }
    }
    out = make_float2(re, im);
  }
  fusedC[dFB[w] + (size_t)jloc * NEp + v] = out;
}

// ---------------- edge_y: exact FIR output near the signal boundaries ----------------
// ye[row][i]: i<1536 -> pos=i ; else pos = 318464 + (i-1536)
__global__ __launch_bounds__(256) void edge_y(const float* __restrict__ x,
                                              const float* __restrict__ h,
                                              float* __restrict__ ye) {
  __shared__ float xl[1280 + 16], hs[1025];
  const int row = blockIdx.y, tid = threadIdx.x;
  const size_t rowoff = (size_t)row * T_LEN;
  const int i0 = blockIdx.x * 256;
  const int pos0 = (i0 < 1536) ? i0 : 318464 + (i0 - 1536);
  for (int i = tid; i < 1025; i += 256) hs[i] = h[i];
  for (int i = tid; i < 1280; i += 256) {
    int g = pos0 - 512 + i;
    xl[i] = ((unsigned)g < (unsigned)T_LEN) ? x[rowoff + g] : 0.0f;
  }
  __syncthreads();
  float acc = 0.0f;
  // y[pos] = sum_m h[m] x[pos+512-m]; xl index = (pos-pos0) + 1024 - m
  const int d = tid + 1024;
  for (int m = 0; m <= 1024; ++m) acc = fmaf(hs[m], xl[d - m], acc);
  ye[(size_t)row * 3072 + i0 + tid] = acc;
}

// ---------------- edge_dft: exact spectrum for frames where y-window exits [0,T) ----------------
__constant__ int eW[8] = {0,0,0,1,2,3,4,5};
__constant__ int eF[8] = {0,1,624,0,0,0,0,0};
__global__ __launch_bounds__(256) void edge_dft(const float* __restrict__ ye,
                                                const float2* __restrict__ coeff,
                                                float* __restrict__ Ibuf) {
  __shared__ float yl[3072];
  const int row = blockIdx.x, tid = threadIdx.x;
  for (int i = tid; i < 3072; i += 256) yl[i] = ye[(size_t)row * 3072 + i];
  __syncthreads();
  const int wv = tid >> 6, lane = tid & 63;
  for (int e = wv; e < 8; e += 4) {
    const int w = eW[e], f = eF[e];
    const int N = cW_N[w];
    const int nb = cW_CB[w + 1] - cW_CB[w];
    for (int jl = 0; jl < nb; ++jl) {
      const float2* cf = coeff + cW_CO[w] + (size_t)jl * N;
      float re = 0.0f, im = 0.0f;
      for (int n = lane; n < N; n += 64) {
        int pos = f * HOPSZ - (N >> 1) + n;
        if ((unsigned)pos < (unsigned)T_LEN) {
          int yi = (pos < 1536) ? pos : (pos - 318464 + 1536);
          float yv = yl[yi];
          float2 cs = cf[n];
          re = fmaf(yv, cs.x, re);
          im = fmaf(yv, cs.y, im);
        }
      }
#pragma unroll
      for (int off = 32; off > 0; off >>= 1) {
        re += __shfl_xor(re, off);
        im += __shfl_xor(im, off);
      }
      if (lane == 0)
        Ibuf[((size_t)row * NFRAMES + f) * NCOMP + (cW_CB[w] + jl)] = re * re + im * im;
    }
  }
}

// ---------------- fused FIR+DFT sparse spectrum -> I[row][f][67] ----------------
#define FPB 16
__device__ __forceinline__ float fold_xor(float a, float b, int m, int lane) {
  float x = (lane & m) ? b : a;
  float y = (lane & m) ? a : b;
  return x + __shfl_xor(y, m);
}

__global__ __launch_bounds__(256) void sparse_dft_fused(const float* __restrict__ x,
                                                        const float2* __restrict__ fusedC,
                                                        float* __restrict__ Ibuf) {
  __shared__ __align__(16) float xs[10752];    // (FPB-1)*512 + 3072
  const int row = blockIdx.y;
  const int f0 = blockIdx.x * FPB;
  const size_t rowoff = (size_t)row * T_LEN;
  const int lo = f0 * HOPSZ - 1536;
  const int tid = threadIdx.x;
  for (int i = tid; i < 10752; i += 256) {
    int g = lo + i;
    xs[i] = ((unsigned)g < (unsigned)T_LEN) ? x[rowoff + g] : 0.0f;
  }
  __syncthreads();
  const int wv = tid >> 6, lane = tid & 63;
  for (int p = dPS[wv]; p < dPS[wv + 1]; ++p) {
    const int w = dPW[p], j0 = dPJ[p], cnt = dPC[p];
    const int NEp = dNEp[w];
    const int stb = dStb[w];
    const float2* c0 = fusedC + dFB[w] + (size_t)(j0 - cW_CB[w]) * NEp;
    const float2* c1 = (cnt == 2) ? c0 + NEp : c0;
    // acc[id]: id = fr | (which<<4); which: 0=re0 1=im0 2=re1 3=im1
    float acc[64];
#pragma unroll
    for (int i = 0; i < 64; ++i) acc[i] = 0.0f;
    for (int u = 2 * lane; u < NEp; u += 128) {
      float4 ca = *(const float4*)(c0 + u);
      float4 cb = *(const float4*)(c1 + u);
      const float* xp = &xs[stb + u];
#pragma unroll
      for (int fr = 0; fr < FPB; ++fr) {
        float2 xv = *(const float2*)&xp[fr * HOPSZ];
        acc[fr]      = fmaf(xv.x, ca.x, acc[fr]);
        acc[16 + fr] = fmaf(xv.x, ca.y, acc[16 + fr]);
        acc[32 + fr] = fmaf(xv.x, cb.x, acc[32 + fr]);
        acc[48 + fr] = fmaf(xv.x, cb.y, acc[48 + fr]);
        acc[fr]      = fmaf(xv.y, ca.z, acc[fr]);
        acc[16 + fr] = fmaf(xv.y, ca.w, acc[16 + fr]);
        acc[32 + fr] = fmaf(xv.y, cb.z, acc[32 + fr]);
        acc[48 + fr] = fmaf(xv.y, cb.w, acc[48 + fr]);
      }
    }
    // butterfly fold: 64 values -> lane l holds full sum of value id=l
#pragma unroll
    for (int k = 0; k < 6; ++k) {
      const int m = 1 << k;
      const int nhalf = 64 >> (k + 1);
#pragma unroll
      for (int i = 0; i < nhalf; ++i) acc[i] = fold_xor(acc[2 * i], acc[2 * i + 1], m, lane);
    }
    float v = acc[0];
    float sq = v * v;
    sq += __shfl_xor(sq, 16);            // re^2 + im^2 lands where bit4==0
    const int fr = lane & 15, which = lane >> 4;
    const int f = f0 + fr;
    const int jb = which >> 1;
    if ((which & 1) == 0 && jb < cnt && f < NFRAMES) {
      bool edge = (f == 0) || (w == 0 && (f == 1 || f == 624));
      if (!edge) Ibuf[((size_t)row * NFRAMES + f) * NCOMP + (j0 + jb)] = sq;
    }
  }
}

// ---------------- E = I@W -> dB -> LUT interp -> n_inst[row][f][150] ----------------
__global__ __launch_bounds__(192) void espec(const float* __restrict__ Ibuf,
                                             const float* __restrict__ Wmat,
                                             const float* __restrict__ lut,
                                             float* __restrict__ ninst) {
  const int blk = blockIdx.x;           // row*625 + f
  const int c = threadIdx.x;
  const float* Irow = Ibuf + (size_t)blk * NCOMP;
  if (c < NCH) {
    float e = 0.0f;
    for (int j = 0; j < NCOMP; ++j) e = fmaf(Irow[j], Wmat[j * NCH + c], e);
    float edb = 10.0f * log10f(e * 2.5e9f + 1e-12f);   // 1/I0 = 2.5e9
    float xv = fminf(fmaxf(edb, 0.0f), 110.0f);
    float u = xv * (87.0f / 110.0f);
    int i0 = (int)u; if (i0 > 86) i0 = 86;
    float fr = u - (float)i0;
    float nv = fmaf(lut[i0 + 1] - lut[i0], fr, lut[i0]);
    ninst[(size_t)blk * NCH + c] = nv;
  }
}

// ---------------- short-term AGC over frames ----------------
__global__ void agc1(const float* __restrict__ ninst, float* __restrict__ stl) {
  int idx = blockIdx.x * 256 + threadIdx.x;
  if (idx >= NROWS * NCH) return;
  int row = idx / NCH, c = idx - row * NCH;
  const float* src = ninst + (size_t)row * NFRAMES * NCH + c;
  float* dst = stl + (size_t)row * NFRAMES * NCH + c;
  float s = 0.0f;
  for (int f = 0; f < NFRAMES; ++f) {
    float xv = src[(size_t)f * NCH];
    float a = (xv > s) ? 0.045f : 0.033f;
    s = a * xv + (1.0f - a) * s;
    dst[(size_t)f * NCH] = s;
  }
}

// ---------------- ERB smoothing + binaural inhibition + channel sum ----------------
__global__ __launch_bounds__(192) void combine(const float* __restrict__ stl,
                                               const float* __restrict__ gauss,
                                               float* __restrict__ outL,
                                               float* __restrict__ outR) {
  __shared__ float sl[NCH + 16], sr[NCH + 16], gsh[17];
  __shared__ float redL[3], redR[3];
  const int bf = blockIdx.x;
  const int b = bf / NFRAMES, f = bf - b * NFRAMES;
  const int tid = threadIdx.x;
  if (tid < NCH + 16) { sl[tid] = 0.0f; sr[tid] = 0.0f; }
  if (tid < 17) gsh[tid] = gauss[tid];
  __syncthreads();
  if (tid < NCH) {
    sl[8 + tid] = stl[((size_t)(b * 2 + 0) * NFRAMES + f) * NCH + tid];
    sr[8 + tid] = stl[((size_t)(b * 2 + 1) * NFRAMES + f) * NCH + tid];
  }
  __syncthreads();
  float vl = 0.0f, vr = 0.0f;
  if (tid < NCH) {
    float smL = 0.0f, smR = 0.0f;
#pragma unroll
    for (int t = 0; t < 17; ++t) {
      smL = fmaf(gsh[t], sl[tid + t], smL);
      smR = fmaf(gsh[t], sr[tid + t], smR);
    }
    vl = smL / coshf(1.5978f * smR);
    vr = smR / coshf(1.5978f * smL);
  }
#pragma unroll
  for (int off = 32; off > 0; off >>= 1) {
    vl += __shfl_xor(vl, off);
    vr += __shfl_xor(vr, off);
  }
  int wv = tid >> 6, lane = tid & 63;
  if (lane == 0) { redL[wv] = vl; redR[wv] = vr; }
  __syncthreads();
  if (tid == 0) {
    outL[bf] = (redL[0] + redL[1] + redL[2]) * 0.25f;
    outR[bf] = (redR[0] + redR[1] + redR[2]) * 0.25f;
  }
}

// ---------------- long-term AGC + outputs ----------------
__global__ void final_k(const float* __restrict__ sLst, const float* __restrict__ sRst,
                        float* __restrict__ out) {
  int b = threadIdx.x;
  if (b >= NB) return;
  float ll = 0.0f, lr = 0.0f, mx = -3.4e38f;
  float* sOut = out;
  float* lOut = out + NB * NFRAMES;
  float* mOut = out + 2 * NB * NFRAMES;
  for (int f = 0; f < NFRAMES; ++f) {
    float a = sLst[b * NFRAMES + f];
    float c = sRst[b * NFRAMES + f];
    sOut[b * NFRAMES + f] = a + c;
    float aa = (a > ll) ? 0.01f : 0.00133f;
    ll = aa * a + (1.0f - aa) * ll;
    float ab = (c > lr) ? 0.01f : 0.00133f;
    lr = ab * c + (1.0f - ab) * lr;
    float lv = ll + lr;
    lOut[b * NFRAMES + f] = lv;
    mx = fmaxf(mx, lv);
  }
  mOut[b] = mx;
}

extern "C" void kernel_launch(void* const* d_in, const int* in_sizes, int n_in,
                              void* d_out, int out_size, void* d_ws, size_t ws_size,
                              hipStream_t stream) {
  const float* audio = (const float*)d_in[0];
  const float* ear   = (const float*)d_in[1];
  const float* lut   = (const float*)d_in[2];
  char* ws = (char*)d_ws;

  float2* fusedC = (float2*)(ws);                       //   820,224 B
  float2* coeffO = (float2*)(ws + 820224);              //   260,608 B
  float*  Wmat   = (float*)(ws + 1080832);              //    40,200 B
  float*  gauss  = (float*)(ws + 1121040);              //        68 B
  float*  yedge  = (float*)(ws + 1121280);              //   393,216 B
  float*  Ibuf   = (float*)(ws + 1514496);              // 5,360,000 B
  float*  ninst  = (float*)(ws + 6874496);              // 12,000,000 B
  float*  stl    = (float*)(ws + 18874496);             // 12,000,000 B
  float*  stlL   = (float*)(ws + 30874496);             //    40,000 B
  float*  stlR   = (float*)(ws + 30914496);             //    40,000 B

  hipLaunchKernelGGL(init_tables, dim3(167), dim3(256), 0, stream, coeffO, Wmat, gauss);
  hipLaunchKernelGGL(init_fused, dim3(414), dim3(256), 0, stream, ear, fusedC);
  hipLaunchKernelGGL(edge_y, dim3(12, 32), dim3(256), 0, stream, audio, ear, yedge);
  hipLaunchKernelGGL(edge_dft, dim3(32), dim3(256), 0, stream, yedge, coeffO, Ibuf);
  hipLaunchKernelGGL(sparse_dft_fused, dim3(40, 32), dim3(256), 0, stream, audio, fusedC, Ibuf);
  hipLaunchKernelGGL(espec, dim3(NROWS * NFRAMES), dim3(192), 0, stream, Ibuf, Wmat, lut, ninst);
  hipLaunchKernelGGL(agc1, dim3(19), dim3(256), 0, stream, ninst, stl);
  hipLaunchKernelGGL(combine, dim3(NB * NFRAMES), dim3(192), 0, stream, stl, gauss, stlL, stlR);
  hipLaunchKernelGGL(final_k, dim3(1), dim3(64), 0, stream, stlL, stlR, (float*)d_out);
}